// Round 6
// baseline (167.688 us; speedup 1.0000x reference)
//
#include <hip/hip_runtime.h>

#define BINS 4096      // 16^3
#define WORDS 2048     // u16-packed: 2 bins per u32 word
#define H_GRID 1024
#define H_BLOCK 256    // 4 waves/block, 4 blocks/CU -> 16 waves/CU
#define CHUNKS 8       // reduce row-chunks: 1024 rows / 8 = 128 rows per chunk
#define R_GRID (16 * CHUNKS)   // 128 reduce blocks
#define R_BLOCK 256

__device__ __forceinline__ int qz(float c) {
    // matches: clip((c * 15.0f).astype(int32), 0, 15); trunc == floor for c >= 0
    int q = (int)(c * 15.0f);
    q = q < 0 ? 0 : q;
    q = q > 15 ? 15 : q;
    return q;
}

__device__ __forceinline__ int bin3(float r, float g, float b) {
    return (qz(r) << 8) | (qz(g) << 4) | qz(b);
}

__device__ __forceinline__ void lds_count(unsigned int* lh, int b) {
    atomicAdd(&lh[b >> 1], 1u << ((b & 1) << 4));
}

// K1: per-block u16-packed LDS histogram, non-atomic coalesced partial flush.
// Per-block point count = 8388608/1024 = 8192 (+tail) < 65535: no u16 overflow.
// Unroll-2: 6 float4 loads in flight per iteration for latency hiding.
__global__ __launch_bounds__(H_BLOCK) void hist_partial_kernel(
        const float* __restrict__ src, unsigned int* __restrict__ partials,
        unsigned int* __restrict__ counter, int n_pts) {
    if (blockIdx.x == 0 && threadIdx.x == 0) *counter = 0;  // for K2's last-block
    __shared__ unsigned int lh[WORDS];
    for (int i = threadIdx.x; i < WORDS; i += H_BLOCK) lh[i] = 0;
    __syncthreads();

    const float4* __restrict__ src4 = (const float4*)src;
    const int n_quads = n_pts >> 2;
    const int tid = blockIdx.x * H_BLOCK + threadIdx.x;
    const int stride = gridDim.x * H_BLOCK;

    int q = tid;
    for (; q + stride < n_quads; q += 2 * stride) {
        float4 a0 = src4[3 * q + 0];
        float4 b0 = src4[3 * q + 1];
        float4 c0 = src4[3 * q + 2];
        int q1 = q + stride;
        float4 a1 = src4[3 * q1 + 0];
        float4 b1 = src4[3 * q1 + 1];
        float4 c1 = src4[3 * q1 + 2];
        lds_count(lh, bin3(a0.x, a0.y, a0.z));
        lds_count(lh, bin3(a0.w, b0.x, b0.y));
        lds_count(lh, bin3(b0.z, b0.w, c0.x));
        lds_count(lh, bin3(c0.y, c0.z, c0.w));
        lds_count(lh, bin3(a1.x, a1.y, a1.z));
        lds_count(lh, bin3(a1.w, b1.x, b1.y));
        lds_count(lh, bin3(b1.z, b1.w, c1.x));
        lds_count(lh, bin3(c1.y, c1.z, c1.w));
    }
    for (; q < n_quads; q += stride) {
        float4 a = src4[3 * q + 0];
        float4 b = src4[3 * q + 1];
        float4 c = src4[3 * q + 2];
        lds_count(lh, bin3(a.x, a.y, a.z));
        lds_count(lh, bin3(a.w, b.x, b.y));
        lds_count(lh, bin3(b.z, b.w, c.x));
        lds_count(lh, bin3(c.y, c.z, c.w));
    }
    if (blockIdx.x == 0) {
        int tail = n_pts & 3;
        if ((int)threadIdx.x < tail) {
            int p = (n_quads << 2) + threadIdx.x;
            lds_count(lh, bin3(src[3 * p], src[3 * p + 1], src[3 * p + 2]));
        }
    }
    __syncthreads();

    // coalesced uint4 flush: 2 passes x 256 lanes x 16 B = 8 KB
    uint4* dst = (uint4*)(partials + (size_t)blockIdx.x * WORDS);
    const uint4* lh4 = (const uint4*)lh;
#pragma unroll
    for (int p = 0; p < WORDS / (H_BLOCK * 4); ++p)
        dst[threadIdx.x + p * H_BLOCK] = lh4[threadIdx.x + p * H_BLOCK];
}

// K2 (fused reduce + loss): 128 blocks sum the u16 partial rows into
// g_part[chunk][bin]; the last block to finish (completion counter) builds the
// target histogram in LDS and computes the final L1 loss.
__global__ __launch_bounds__(R_BLOCK) void reduce_loss_kernel(
        const unsigned int* __restrict__ partials,
        unsigned int* __restrict__ g_part, unsigned int* __restrict__ counter,
        const float* __restrict__ tgt, float* __restrict__ out,
        int n_src, int n_tgt) {
    const int bin   = (blockIdx.x & 15) * R_BLOCK + threadIdx.x;
    const int chunk = blockIdx.x >> 4;
    const int r0    = chunk * (H_GRID / CHUNKS);
    const unsigned short* __restrict__ p16 = (const unsigned short*)partials;
    unsigned int s = 0;
#pragma unroll 8
    for (int r = 0; r < H_GRID / CHUNKS; ++r)
        s += (unsigned int)p16[(size_t)(r0 + r) * BINS + bin];
    g_part[chunk * BINS + bin] = s;

    // ---- completion counter: last block computes the loss ----
    __threadfence();   // release: make g_part writes device-visible
    __syncthreads();
    __shared__ int is_last;
    if (threadIdx.x == 0) {
        unsigned int prev = atomicAdd(counter, 1u);
        is_last = (prev == (unsigned int)(R_GRID - 1)) ? 1 : 0;
    }
    __syncthreads();
    if (!is_last) return;
    __threadfence();   // acquire: observe all g_part writes

    // ---- target histogram into LDS (u32, counts tiny) ----
    __shared__ unsigned int th[BINS];
    for (int i = threadIdx.x; i < BINS; i += R_BLOCK) th[i] = 0;
    __syncthreads();
    const float4* __restrict__ t4 = (const float4*)tgt;
    const int tq = n_tgt >> 2;
    for (int q = threadIdx.x; q < tq; q += R_BLOCK) {
        float4 a = t4[3 * q + 0];
        float4 b = t4[3 * q + 1];
        float4 c = t4[3 * q + 2];
        atomicAdd(&th[bin3(a.x, a.y, a.z)], 1u);
        atomicAdd(&th[bin3(a.w, b.x, b.y)], 1u);
        atomicAdd(&th[bin3(b.z, b.w, c.x)], 1u);
        atomicAdd(&th[bin3(c.y, c.z, c.w)], 1u);
    }
    {
        int tail = n_tgt & 3;
        if ((int)threadIdx.x < tail) {
            int p = (tq << 2) + threadIdx.x;
            atomicAdd(&th[bin3(tgt[3 * p], tgt[3 * p + 1], tgt[3 * p + 2])], 1u);
        }
    }
    __syncthreads();

    // ---- L1 loss (f64 accumulation, deterministic) ----
    const double ns = (double)n_src + 1e-8;
    const double nt = (double)n_tgt + 1e-8;
    double acc = 0.0;
    for (int i = threadIdx.x; i < BINS; i += R_BLOCK) {
        unsigned int sv = 0;
#pragma unroll
        for (int c = 0; c < CHUNKS; ++c) sv += g_part[c * BINS + i];
        acc += fabs((double)sv / ns - (double)th[i] / nt);
    }
    for (int off = 32; off > 0; off >>= 1) acc += __shfl_down(acc, off);
    __shared__ double red[R_BLOCK / 64];
    if ((threadIdx.x & 63) == 0) red[threadIdx.x >> 6] = acc;
    __syncthreads();
    if (threadIdx.x == 0) {
        double t = 0.0;
        for (int w = 0; w < R_BLOCK / 64; ++w) t += red[w];
        out[0] = (float)(t / (double)BINS);
    }
}

extern "C" void kernel_launch(void* const* d_in, const int* in_sizes, int n_in,
                              void* d_out, int out_size, void* d_ws, size_t ws_size,
                              hipStream_t stream) {
    const float* src = (const float*)d_in[0];
    const float* tgt = (const float*)d_in[1];
    const int n_src = in_sizes[0] / 3;
    const int n_tgt = in_sizes[1] / 3;

    unsigned int* partials = (unsigned int*)d_ws;                 // 1024*2048 u32 = 8 MB
    unsigned int* g_part   = partials + (size_t)H_GRID * WORDS;   // 8*4096 u32 = 128 KB
    unsigned int* counter  = g_part + CHUNKS * BINS;              // 1 u32

    hist_partial_kernel<<<H_GRID, H_BLOCK, 0, stream>>>(src, partials, counter, n_src);
    reduce_loss_kernel<<<R_GRID, R_BLOCK, 0, stream>>>(
        partials, g_part, counter, tgt, (float*)d_out, n_src, n_tgt);
}

// Round 8
// 153.785 us; speedup vs baseline: 1.0904x; 1.0904x over previous
//
#include <hip/hip_runtime.h>

#define BINS 4096      // 16^3
#define WORDS 2048     // u16-packed: 2 bins per u32 word
#define H_GRID 1024
#define H_BLOCK 256    // 4 waves/block, 4 blocks/CU -> 16 waves/CU
#define CHUNKS 8       // K2 row-chunks: 1024 rows / 8 = 128 rows per chunk

typedef float ntf4 __attribute__((ext_vector_type(4)));  // native vec for NT loads

__device__ __forceinline__ int qz(float c) {
    // matches: clip((c * 15.0f).astype(int32), 0, 15); trunc == floor for c >= 0
    int q = (int)(c * 15.0f);
    q = q < 0 ? 0 : q;
    q = q > 15 ? 15 : q;
    return q;
}

__device__ __forceinline__ int bin3(float r, float g, float b) {
    return (qz(r) << 8) | (qz(g) << 4) | qz(b);
}

// K1: per-block u16-packed LDS histogram, non-atomic coalesced partial flush.
// Per-block point count = 8388608/1024 = 8192 (+3 tail) < 65535: no u16
// overflow, no carry across halfwords. Source loads are non-temporal (read
// exactly once; don't cycle L2).
__global__ __launch_bounds__(H_BLOCK) void hist_partial_kernel(
        const float* __restrict__ src, unsigned int* __restrict__ partials,
        int n_pts) {
    __shared__ unsigned int lh[WORDS];
    for (int i = threadIdx.x; i < WORDS; i += H_BLOCK) lh[i] = 0;
    __syncthreads();

    const ntf4* __restrict__ src4 = (const ntf4*)src;
    const int n_quads = n_pts >> 2;
    const int tid = blockIdx.x * H_BLOCK + threadIdx.x;
    const int stride = gridDim.x * H_BLOCK;
    for (int q = tid; q < n_quads; q += stride) {
        ntf4 a = __builtin_nontemporal_load(&src4[3 * q + 0]);
        ntf4 b = __builtin_nontemporal_load(&src4[3 * q + 1]);
        ntf4 c = __builtin_nontemporal_load(&src4[3 * q + 2]);
        int b0 = bin3(a.x, a.y, a.z);
        int b1 = bin3(a.w, b.x, b.y);
        int b2 = bin3(b.z, b.w, c.x);
        int b3 = bin3(c.y, c.z, c.w);
        atomicAdd(&lh[b0 >> 1], 1u << ((b0 & 1) << 4));
        atomicAdd(&lh[b1 >> 1], 1u << ((b1 & 1) << 4));
        atomicAdd(&lh[b2 >> 1], 1u << ((b2 & 1) << 4));
        atomicAdd(&lh[b3 >> 1], 1u << ((b3 & 1) << 4));
    }
    if (blockIdx.x == 0) {
        int tail = n_pts & 3;
        if ((int)threadIdx.x < tail) {
            int p = (n_quads << 2) + threadIdx.x;
            int bb = bin3(src[3 * p], src[3 * p + 1], src[3 * p + 2]);
            atomicAdd(&lh[bb >> 1], 1u << ((bb & 1) << 4));
        }
    }
    __syncthreads();

    // coalesced uint4 flush: 2 passes x 256 lanes x 16 B = 8 KB
    uint4* dst = (uint4*)(partials + (size_t)blockIdx.x * WORDS);
    const uint4* lh4 = (const uint4*)lh;
#pragma unroll
    for (int p = 0; p < WORDS / (H_BLOCK * 4); ++p)
        dst[threadIdx.x + p * H_BLOCK] = lh4[threadIdx.x + p * H_BLOCK];
}

// K2: parallel column-sum of the 1024 u16 partial rows.
// Grid = 16 bin-groups x 8 row-chunks = 128 blocks x 256 threads.
// Each thread sums 128 u16s for one bin (coalesced: consecutive threads read
// consecutive u16s), writes g_part[chunk][bin] non-atomically.
__global__ __launch_bounds__(256) void reduce_kernel(
        const unsigned int* __restrict__ partials,
        unsigned int* __restrict__ g_part) {
    const int bin   = (blockIdx.x & 15) * 256 + threadIdx.x;
    const int chunk = blockIdx.x >> 4;
    const int r0    = chunk * (H_GRID / CHUNKS);
    const unsigned short* __restrict__ p16 = (const unsigned short*)partials;
    unsigned int s = 0;
#pragma unroll 8
    for (int r = 0; r < H_GRID / CHUNKS; ++r)
        s += (unsigned int)p16[(size_t)(r0 + r) * BINS + bin];
    g_part[chunk * BINS + bin] = s;
}

// K3: single block -- target hist in LDS, then L1 loss (f64, deterministic).
// Source bin totals = sum of the 8 chunk-partials.
__global__ __launch_bounds__(1024) void loss_kernel(
        const float* __restrict__ tgt, const unsigned int* __restrict__ g_part,
        float* __restrict__ out, int n_src, int n_tgt) {
    __shared__ unsigned int th[BINS];
    for (int i = threadIdx.x; i < BINS; i += 1024) th[i] = 0;
    __syncthreads();

    const float4* __restrict__ t4 = (const float4*)tgt;
    const int tq = n_tgt >> 2;
    for (int q = threadIdx.x; q < tq; q += 1024) {
        float4 a = t4[3 * q + 0];
        float4 b = t4[3 * q + 1];
        float4 c = t4[3 * q + 2];
        atomicAdd(&th[bin3(a.x, a.y, a.z)], 1u);
        atomicAdd(&th[bin3(a.w, b.x, b.y)], 1u);
        atomicAdd(&th[bin3(b.z, b.w, c.x)], 1u);
        atomicAdd(&th[bin3(c.y, c.z, c.w)], 1u);
    }
    {
        int tail = n_tgt & 3;
        if ((int)threadIdx.x < tail) {
            int p = (tq << 2) + threadIdx.x;
            atomicAdd(&th[bin3(tgt[3 * p], tgt[3 * p + 1], tgt[3 * p + 2])], 1u);
        }
    }
    __syncthreads();

    const double ns = (double)n_src + 1e-8;
    const double nt = (double)n_tgt + 1e-8;
    double acc = 0.0;
    for (int i = threadIdx.x; i < BINS; i += 1024) {
        unsigned int sv = 0;
#pragma unroll
        for (int c = 0; c < CHUNKS; ++c) sv += g_part[c * BINS + i];
        acc += fabs((double)sv / ns - (double)th[i] / nt);
    }

    for (int off = 32; off > 0; off >>= 1) acc += __shfl_down(acc, off);
    __shared__ double red[16];
    if ((threadIdx.x & 63) == 0) red[threadIdx.x >> 6] = acc;
    __syncthreads();
    if (threadIdx.x == 0) {
        double s = 0.0;
        for (int w = 0; w < 16; ++w) s += red[w];
        out[0] = (float)(s / (double)BINS);
    }
}

extern "C" void kernel_launch(void* const* d_in, const int* in_sizes, int n_in,
                              void* d_out, int out_size, void* d_ws, size_t ws_size,
                              hipStream_t stream) {
    const float* src = (const float*)d_in[0];
    const float* tgt = (const float*)d_in[1];
    const int n_src = in_sizes[0] / 3;
    const int n_tgt = in_sizes[1] / 3;

    unsigned int* partials = (unsigned int*)d_ws;                 // 1024*2048 u32 = 8 MB
    unsigned int* g_part   = partials + (size_t)H_GRID * WORDS;   // 8*4096 u32 = 128 KB

    hist_partial_kernel<<<H_GRID, H_BLOCK, 0, stream>>>(src, partials, n_src);
    reduce_kernel<<<16 * CHUNKS, 256, 0, stream>>>(partials, g_part);
    loss_kernel<<<1, 1024, 0, stream>>>(tgt, g_part, (float*)d_out, n_src, n_tgt);
}